// Round 1
// baseline (155.848 us; speedup 1.0000x reference)
//
#include <hip/hip_runtime.h>

// CritiGraph fused loss kernel, MI355X (gfx950).
//
// Key facts exploited:
//  * voc_emb is DEAD in the reference (eu_val[:,64:] never used) -> never read (saves 67MB).
//  * cos_similarity(c1,c2) = sgn * (clz(|c1|^|c2| + 1)/16 - 1) with sgn = sign(c1)*sign(c2).
//    Packing (sign<<31)|abs lets one XOR produce both the sign product (bit31) and abs-xor.
//  * loss_dyn_dyn = kl_const - sum_s p_eu*ct + lse_s(ct);  loss_dyn_sta = lse_v(20ct) - 20ct[tar].
//  * Logits bounded (|ct|<=1.25, |20ct|<=25) -> single-pass sum-of-exps, no max subtraction.

#define Tn   512
#define NC   65
#define TPd  8
#define NTn  64
#define KV   128
#define Sn   192
#define Dn   256

__global__ __launch_bounds__(256) void critigraph_kernel(
    const int*   __restrict__ cur_tar,   // (T)
    const int*   __restrict__ cnc_loc,   // (T, NC, TP)
    const int*   __restrict__ sta_loc,   // (T, TP)
    const int*   __restrict__ ttn_loc,   // (T, NT, TP)
    const int*   __restrict__ voc_loc,   // (T, KV, TP)
    const float* __restrict__ sta_emb,   // (T, D)
    const float* __restrict__ ttn_emb,   // (T, NT, D)
    float*       __restrict__ out)       // [dd: T*NC*TP][ds: T*NC*TP]
{
    __shared__ int   s_apos[Sn * TPd];   // packed (sign<<31)|abs of pos_loc
    __shared__ float s_base[Sn * TPd];   // (cos_sum[s]-cos_sp[s][p]) * (s<64 ? 0.125 : 2.5)
    __shared__ float s_csum[Sn];
    __shared__ float s_peu[NTn];
    __shared__ float s_eu[NTn];
    __shared__ int   s_cnc[NC * TPd];    // packed cnc_loc
    __shared__ int   s_sta[TPd];
    __shared__ float s_kl;

    const int t    = blockIdx.x;
    const int tid  = threadIdx.x;
    const int lane = tid & 63;
    const int wv   = tid >> 6;

    // ---- stage sta_loc / cnc_loc (packed) ----
    if (tid < TPd) {
        int v = sta_loc[t * TPd + tid];
        s_sta[tid] = (v < 0) ? (int)(0x80000000u | (unsigned)(-v)) : v;
    }
    for (int i = tid; i < NC * TPd; i += 256) {
        int v = cnc_loc[t * NC * TPd + i];
        s_cnc[i] = (v < 0) ? (int)(0x80000000u | (unsigned)(-v)) : v;
    }
    __syncthreads();

    // ---- pos packed + cos_sp (cos_sp temporarily in s_base) ----
    for (int i = tid; i < Sn * TPd; i += 256) {
        int s = i >> 3;
        int v = (s < NTn) ? ttn_loc[t * NTn * TPd + i]
                          : voc_loc[t * KV * TPd + (i - NTn * TPd)];
        int packed = (v < 0) ? (int)(0x80000000u | (unsigned)(-v)) : v;
        s_apos[i] = packed;
        int   y    = packed ^ s_sta[i & 7];
        int   x    = (y & 0x7fffffff) + 1;
        float fclz = (float)__clz(x);
        float c    = fmaf(fclz, 0.0625f, -1.0f);          // 1 - e/16, e = 32-clz
        c = __int_as_float(__float_as_int(c) ^ (y & 0x80000000));
        s_base[i] = c;                                     // = cos_sp
    }
    __syncthreads();

    if (tid < Sn) {
        float a = 0.f;
        #pragma unroll
        for (int p = 0; p < TPd; ++p) a += s_base[tid * TPd + p];
        s_csum[tid] = a;
    }
    __syncthreads();

    for (int i = tid; i < Sn * TPd; i += 256) {
        int s = i >> 3;
        float scale = (s < NTn) ? 0.125f : 2.5f;           // (20*TEMP)/TP ; ((20*TEMP)/TP)/TEMP
        s_base[i] = (s_csum[s] - s_base[i]) * scale;
    }

    // ---- eu = sta_emb . ttn_emb (one wave per row, lane-per-float4, coalesced) ----
    {
        const float4* a4 = (const float4*)(sta_emb + (size_t)t * Dn);
        float4 a = a4[lane];
        for (int s = wv; s < NTn; s += 4) {
            const float4* b4 = (const float4*)(ttn_emb + ((size_t)t * NTn + s) * Dn);
            float4 b = b4[lane];
            float d = a.x * b.x + a.y * b.y + a.z * b.z + a.w * b.w;
            #pragma unroll
            for (int m = 1; m < 64; m <<= 1) d += __shfl_xor(d, m);
            if (lane == 0) s_eu[s] = d;                    // 20*TEMP = 1.0
        }
    }
    __syncthreads();

    // ---- softmax over eu (wave 0), kl_const = sum p_eu*lp_eu ----
    if (tid < 64) {
        float e  = s_eu[tid];
        float mx = e;
        #pragma unroll
        for (int m = 1; m < 64; m <<= 1) mx = fmaxf(mx, __shfl_xor(mx, m));
        float ex = __expf(e - mx);
        float z  = ex;
        #pragma unroll
        for (int m = 1; m < 64; m <<= 1) z += __shfl_xor(z, m);
        float pe = ex / z;
        s_peu[tid] = pe;
        float kls = pe * ((e - mx) - __logf(z));
        #pragma unroll
        for (int m = 1; m < 64; m <<= 1) kls += __shfl_xor(kls, m);
        if (tid == 0) s_kl = kls;
    }
    __syncthreads();

    // ---- phase B: 8-lane group per (c,p) pair; wave handles 8 p's of one c per round ----
    const int   tar = cur_tar[t];
    const float kl  = s_kl;
    const int   g   = lane >> 3;   // p
    const int   sub = lane & 7;    // s-slice within group
    float* out_dd = out + (size_t)t * NC * TPd;
    float* out_ds = out + (size_t)Tn * NC * TPd + (size_t)t * NC * TPd;

    for (int r = wv; r < NC; r += 4) {                     // r == c
        const int acnc = s_cnc[r * TPd + g];

        // dyn: s in [0,64)
        float sum = 0.f, dot = 0.f;
        #pragma unroll
        for (int k = 0; k < 8; ++k) {
            int   s    = sub + 8 * k;
            int   y    = s_apos[s * TPd + g] ^ acnc;
            int   x    = (y & 0x7fffffff) + 1;
            float fclz = (float)__clz(x);
            float cc   = fmaf(fclz, 0.0078125f, -0.125f);  // cos * 0.125, pre-scaled
            cc = __int_as_float(__float_as_int(cc) ^ (y & 0x80000000));
            float ct = s_base[s * TPd + g] + cc;           // full ct (|ct| <= 1.25)
            sum += __expf(ct);
            dot  = fmaf(s_peu[s], ct, dot);
        }
        #pragma unroll
        for (int m = 1; m < 8; m <<= 1) {
            sum += __shfl_xor(sum, m);
            dot += __shfl_xor(dot, m);
        }
        float loss_dd = kl - dot + __logf(sum);

        // sta: vocab v in [0,128)
        float sum2 = 0.f, tgt = 0.f;
        #pragma unroll
        for (int k = 0; k < 16; ++k) {
            int   vv   = sub + 8 * k;
            int   s    = NTn + vv;
            int   y    = s_apos[s * TPd + g] ^ acnc;
            int   x    = (y & 0x7fffffff) + 1;
            float fclz = (float)__clz(x);
            float cc   = fmaf(fclz, 0.15625f, -2.5f);      // cos * 2.5, pre-scaled
            cc = __int_as_float(__float_as_int(cc) ^ (y & 0x80000000));
            float ct20 = s_base[s * TPd + g] + cc;         // |ct20| <= 25
            sum2 += __expf(ct20);
            tgt = (vv == tar) ? ct20 : tgt;                // only owner lane nonzero
        }
        #pragma unroll
        for (int m = 1; m < 8; m <<= 1) {
            sum2 += __shfl_xor(sum2, m);
            tgt  += __shfl_xor(tgt, m);                    // sum-reduce picks owner's value
        }
        if (sub == 0) {
            out_dd[r * TPd + g] = loss_dd;
            out_ds[r * TPd + g] = __logf(sum2) - tgt;
        }
    }
}

extern "C" void kernel_launch(void* const* d_in, const int* in_sizes, int n_in,
                              void* d_out, int out_size, void* d_ws, size_t ws_size,
                              hipStream_t stream) {
    (void)in_sizes; (void)n_in; (void)d_ws; (void)ws_size; (void)out_size;
    const int*   cur_tar = (const int*)  d_in[0];
    const int*   cnc_loc = (const int*)  d_in[1];
    const int*   sta_loc = (const int*)  d_in[2];
    const int*   ttn_loc = (const int*)  d_in[3];
    const int*   voc_loc = (const int*)  d_in[4];
    const float* sta_emb = (const float*)d_in[5];
    const float* ttn_emb = (const float*)d_in[6];
    // d_in[7] (voc_emb) is intentionally unused: it only feeds eu_val[:,64:], which
    // the reference discards.
    critigraph_kernel<<<Tn, 256, 0, stream>>>(cur_tar, cnc_loc, sta_loc, ttn_loc,
                                              voc_loc, sta_emb, ttn_emb, (float*)d_out);
}